// Round 8
// baseline (467.693 us; speedup 1.0000x reference)
//
#include <hip/hip_runtime.h>

#define NKV 8192
#define NB 64

typedef __attribute__((ext_vector_type(8))) short short8;
typedef __attribute__((ext_vector_type(8))) unsigned short ushort8;
typedef __attribute__((ext_vector_type(4))) unsigned short usx4;
typedef __attribute__((ext_vector_type(4))) float f32x4;

__device__ __forceinline__ float bf2f(unsigned short u) {
  return __uint_as_float(((unsigned int)u) << 16);
}
__device__ __forceinline__ unsigned short f2bf(float f) {
  unsigned int x = __float_as_uint(f);
  return (unsigned short)((x + 0x7fffu + ((x >> 16) & 1u)) >> 16);
}
__device__ __forceinline__ float sigm(float x) { return 1.f / (1.f + __expf(-x)); }

// ---------------------------------------------------------------------------
// K0: convert Wk/Wv to bf16 MFMA fragments once (W^T chunks).
// ---------------------------------------------------------------------------
__global__ __launch_bounds__(256) void k_wprep(
    const float* __restrict__ Wk, const float* __restrict__ Wv,
    unsigned short* __restrict__ wf) {
  int idx = blockIdx.x * 256 + threadIdx.x;  // 0..1023
  int lane = idx & 63, ct = (idx >> 6) & 7, kf = idx >> 9;
  int half = lane >> 4, rlo = lane & 15;
  const float* W = (ct < 4) ? Wk : Wv;
  int cc = (ct & 3) * 16 + rlo;
  ushort8 pk;
#pragma unroll
  for (int i = 0; i < 8; ++i)
    pk[i] = f2bf(W[(kf * 32 + half * 8 + i) * 64 + cc]);
  *(ushort8*)(wf + (size_t)idx * 8) = pk;
}

// ---------------------------------------------------------------------------
// K1: LN + k/v projection (R6 form: no prefetch, 8 tiles/wave, grid 1024).
// ---------------------------------------------------------------------------
__global__ __launch_bounds__(256) void k_proj(
    const float* __restrict__ x, const float* __restrict__ gin,
    const float* __restrict__ bin, const unsigned short* __restrict__ wf,
    unsigned short* __restrict__ kv) {
  const int lane = threadIdx.x & 63;
  const int wave = threadIdx.x >> 6;
  const int half = lane >> 4, rlo = lane & 15;

  short8 bfr[2][8];
  const ushort8* wf8 = (const ushort8*)wf;
#pragma unroll
  for (int kf = 0; kf < 2; ++kf)
#pragma unroll
    for (int ct = 0; ct < 8; ++ct)
      bfr[kf][ct] = (short8)wf8[(kf * 8 + ct) * 64 + lane];

  float g0[8], g1[8], bb0[8], bb1[8];
#pragma unroll
  for (int i = 0; i < 8; ++i) {
    g0[i] = gin[half * 8 + i];      bb0[i] = bin[half * 8 + i];
    g1[i] = gin[32 + half * 8 + i]; bb1[i] = bin[32 + half * 8 + i];
  }
  long tok0 = ((long)blockIdx.x * 4 + wave) * 128;
  for (int tile = 0; tile < 8; ++tile) {
    long row = tok0 + tile * 16 + rlo;
    const f32x4* p4 = (const f32x4*)(x + row * 64);
    f32x4 u0 = p4[half * 2], u1 = p4[half * 2 + 1];
    f32x4 u2 = p4[8 + half * 2], u3 = p4[9 + half * 2];
    float s = 0.f, ss = 0.f;
#pragma unroll
    for (int i = 0; i < 4; ++i) {
      s += u0[i] + u1[i] + u2[i] + u3[i];
      ss = fmaf(u0[i], u0[i], fmaf(u1[i], u1[i], fmaf(u2[i], u2[i], fmaf(u3[i], u3[i], ss))));
    }
    s += __shfl_xor(s, 16); ss += __shfl_xor(ss, 16);
    s += __shfl_xor(s, 32); ss += __shfl_xor(ss, 32);
    float m = s * 0.015625f;
    float var = ss * 0.015625f - m * m;
    float rs = rsqrtf(var + 1e-5f);
    short8 a0, a1;
#pragma unroll
    for (int i = 0; i < 4; ++i) {
      a0[i]     = (short)f2bf((u0[i] - m) * rs * g0[i]     + bb0[i]);
      a0[i + 4] = (short)f2bf((u1[i] - m) * rs * g0[i + 4] + bb0[i + 4]);
      a1[i]     = (short)f2bf((u2[i] - m) * rs * g1[i]     + bb1[i]);
      a1[i + 4] = (short)f2bf((u3[i] - m) * rs * g1[i + 4] + bb1[i + 4]);
    }
    long t = tok0 + tile * 16 + rlo;
#pragma unroll
    for (int ct = 0; ct < 8; ++ct) {
      f32x4 acc = {0.f, 0.f, 0.f, 0.f};
      acc = __builtin_amdgcn_mfma_f32_16x16x32_bf16(bfr[0][ct], a0, acc, 0, 0, 0);
      acc = __builtin_amdgcn_mfma_f32_16x16x32_bf16(bfr[1][ct], a1, acc, 0, 0, 0);
      float sc = (ct < 4) ? 0.25f : 1.f;
      usx4 pk;
#pragma unroll
      for (int r = 0; r < 4; ++r) pk[r] = f2bf(acc[r] * sc);
      *(usx4*)(kv + t * 128 + ct * 16 + half * 4) = pk;
    }
  }
}

// ---------------------------------------------------------------------------
// K_prep: one wave per (batch,slot). grid 512 x 64.
// ---------------------------------------------------------------------------
__global__ __launch_bounds__(64) void k_prep(
    const float* __restrict__ slots_in, const float* __restrict__ g_slot,
    const float* __restrict__ b_slot, const float* __restrict__ Wq,
    float* __restrict__ slots_buf, float* __restrict__ qbuf,
    float* __restrict__ Sg, float* __restrict__ Wg) {
  int b = blockIdx.x >> 3, s = blockIdx.x & 7, d = threadIdx.x;
  __shared__ float l2_s[64];
  float x = slots_in[(b * 8 + s) * 64 + d];
  slots_buf[(b * 8 + s) * 64 + d] = x;
  float sum = x, sq = x * x;
#pragma unroll
  for (int msk = 1; msk < 64; msk <<= 1) { sum += __shfl_xor(sum, msk); sq += __shfl_xor(sq, msk); }
  float mean = sum * 0.015625f, var = sq * 0.015625f - mean * mean;
  float ln = (x - mean) * rsqrtf(var + 1e-5f) * g_slot[d] + b_slot[d];
  l2_s[d] = ln;
  __syncthreads();
  float acc = 0.f;
#pragma unroll 8
  for (int j = 0; j < 64; ++j) acc = fmaf(l2_s[j], Wq[j * 64 + d], acc);
  acc *= 0.25f;
  int hh = d >> 4, dh = d & 15, hq = hh * 8 + s;
  qbuf[(b * 32 + hq) * 16 + dh] = acc;
  if (d < 4) Sg[b * 32 + d * 8 + s] = 0.f;
  Wg[(b * 32 + hq) * 16 + dh] = 0.f;
}

// ---------------------------------------------------------------------------
// K_qfrag: build block-diagonal Qmat^T bf16 A-fragments per batch.
// qfrag[(b*4 + m*2 + kc)*64 + lane] = ushort8: A[m*16+rlo][kc*32+half*8+i].
// grid 64 x 64.
// ---------------------------------------------------------------------------
__global__ __launch_bounds__(64) void k_qfrag(
    const float* __restrict__ qbuf, unsigned short* __restrict__ qfrag) {
  int b = blockIdx.x, lane = threadIdx.x;
  int half = lane >> 4, rlo = lane & 15;
#pragma unroll
  for (int m = 0; m < 2; ++m) {
    int hq = m * 16 + rlo, h = hq >> 3;
#pragma unroll
    for (int kc = 0; kc < 2; ++kc) {
      ushort8 pk;
#pragma unroll
      for (int i = 0; i < 8; ++i) {
        int d = kc * 32 + half * 8 + i;
        float v = ((d >> 4) == h) ? qbuf[(b * 32 + hq) * 16 + (d & 15)] : 0.f;
        pk[i] = f2bf(v);
      }
      *(ushort8*)(qfrag + ((size_t)(b * 4 + m * 2 + kc) * 64 + lane) * 8) = pk;
    }
  }
}

// ---------------------------------------------------------------------------
// K2: MFMA attention pass. Per wave: 64 tokens.
//   logits = Qmat^T (32hq x 64d, block-diag) x K^T (64d x 64tok): 16 MFMAs.
//   C: col=rlo=token, row=m*16+half*4+r=hq -> lane holds 8 hq x 4 tokens.
//   softmax over 32 hq per token: local 8-sum + shfl_xor(16,32).
//   PV: attn^T (slot x tok, via LDS bf16) x v (tok x dh): 8 MFMAs (4 heads).
//   S: per-lane accum + 4-step rlo shfl tree + atomicAdd.
// grid (B*32) x 256.
// ---------------------------------------------------------------------------
template <int IT>
__global__ __launch_bounds__(256) void k_attn(
    const unsigned short* __restrict__ kv, const unsigned short* __restrict__ qfrag,
    float* __restrict__ Sg, float* __restrict__ Wg,
    float* __restrict__ vis) {
  constexpr bool last = (IT == 2);
  const int PS = 34;  // P row stride in halfs (pad vs 32 to spread banks)
  int b = blockIdx.x >> 5, chunk = blockIdx.x & 31;
  int lane = threadIdx.x & 63, wave = threadIdx.x >> 6;
  int half = lane >> 4, rlo = lane & 15;
  __shared__ unsigned short P[4][64 * PS];
  __shared__ float Wred[4][512];
  int t0 = chunk * 256 + wave * 64;

  short8 afr[2][2];
  const ushort8* qf8 = (const ushort8*)qfrag;
#pragma unroll
  for (int m = 0; m < 2; ++m)
#pragma unroll
    for (int kc = 0; kc < 2; ++kc)
      afr[m][kc] = (short8)qf8[(b * 4 + m * 2 + kc) * 64 + lane];

  float Sacc[2][4];
#pragma unroll
  for (int m = 0; m < 2; ++m)
#pragma unroll
    for (int r = 0; r < 4; ++r) Sacc[m][r] = 0.f;

#pragma unroll
  for (int nt = 0; nt < 4; ++nt) {
    long rowb = ((long)(b * NKV) + t0 + nt * 16 + rlo) * 128;
    short8 bk0 = *(const short8*)(kv + rowb + half * 8);        // d 0..31 chunk
    short8 bk1 = *(const short8*)(kv + rowb + 32 + half * 8);   // d 32..63
    f32x4 acc0 = {0.f, 0.f, 0.f, 0.f}, acc1 = {0.f, 0.f, 0.f, 0.f};
    acc0 = __builtin_amdgcn_mfma_f32_16x16x32_bf16(afr[0][0], bk0, acc0, 0, 0, 0);
    acc0 = __builtin_amdgcn_mfma_f32_16x16x32_bf16(afr[0][1], bk1, acc0, 0, 0, 0);
    acc1 = __builtin_amdgcn_mfma_f32_16x16x32_bf16(afr[1][0], bk0, acc1, 0, 0, 0);
    acc1 = __builtin_amdgcn_mfma_f32_16x16x32_bf16(afr[1][1], bk1, acc1, 0, 0, 0);
    // softmax over 32 hq for this lane's token (nt*16+rlo)
    float e0[4], e1[4], ssum = 0.f;
#pragma unroll
    for (int r = 0; r < 4; ++r) {
      e0[r] = __expf(acc0[r]); e1[r] = __expf(acc1[r]);
      ssum += e0[r] + e1[r];
    }
    ssum += __shfl_xor(ssum, 16);
    ssum += __shfl_xor(ssum, 32);
    float rs = __builtin_amdgcn_rcpf(ssum);
    float a0[4], a1[4];
#pragma unroll
    for (int r = 0; r < 4; ++r) {
      a0[r] = e0[r] * rs; a1[r] = e1[r] * rs;
      Sacc[0][r] += a0[r]; Sacc[1][r] += a1[r];
    }
    // pack attn -> P[token][hq] bf16
    int off = (nt * 16 + rlo) * PS;
    unsigned int w00 = (unsigned int)f2bf(a0[0]) | ((unsigned int)f2bf(a0[1]) << 16);
    unsigned int w01 = (unsigned int)f2bf(a0[2]) | ((unsigned int)f2bf(a0[3]) << 16);
    unsigned int w10 = (unsigned int)f2bf(a1[0]) | ((unsigned int)f2bf(a1[1]) << 16);
    unsigned int w11 = (unsigned int)f2bf(a1[2]) | ((unsigned int)f2bf(a1[3]) << 16);
    *(unsigned int*)(&P[wave][off + half * 4])      = w00;
    *(unsigned int*)(&P[wave][off + half * 4 + 2])  = w01;
    *(unsigned int*)(&P[wave][off + 16 + half * 4]) = w10;
    *(unsigned int*)(&P[wave][off + 16 + half * 4 + 2]) = w11;
    if (last) {
      float vl[4];
#pragma unroll
      for (int r = 0; r < 4; ++r) {
        vl[r] = a0[r] + a1[r];
        vl[r] += __shfl_xor(vl[r], 32);
      }
      if (half < 2) {
        long tt = (long)b * NKV + t0 + nt * 16 + rlo;
#pragma unroll
        for (int r = 0; r < 4; ++r) vis[tt * 8 + (half & 1) * 4 + r] = vl[r];
      }
    }
  }
  // S reduce over rlo and atomic
#pragma unroll
  for (int m = 0; m < 2; ++m)
#pragma unroll
    for (int r = 0; r < 4; ++r) {
      Sacc[m][r] += __shfl_xor(Sacc[m][r], 1);
      Sacc[m][r] += __shfl_xor(Sacc[m][r], 2);
      Sacc[m][r] += __shfl_xor(Sacc[m][r], 4);
      Sacc[m][r] += __shfl_xor(Sacc[m][r], 8);
    }
  if (rlo == 0) {
#pragma unroll
    for (int m = 0; m < 2; ++m)
#pragma unroll
      for (int r = 0; r < 4; ++r)
        atomicAdd(&Sg[b * 32 + m * 16 + half * 4 + r], Sacc[m][r]);
  }
  // PV per head: attn^T (from P) x v (from global)
#pragma unroll
  for (int h = 0; h < 4; ++h) {
    f32x4 wacc = {0.f, 0.f, 0.f, 0.f};
#pragma unroll
    for (int kc2 = 0; kc2 < 2; ++kc2) {
      short8 af, bf;
#pragma unroll
      for (int i = 0; i < 8; ++i) {
        af[i] = (short)P[wave][(kc2 * 32 + half * 8 + i) * PS + h * 8 + (rlo & 7)];
        bf[i] = (short)kv[((long)(b * NKV) + t0 + kc2 * 32 + half * 8 + i) * 128 + 64 + h * 16 + rlo];
      }
      wacc = __builtin_amdgcn_mfma_f32_16x16x32_bf16(af, bf, wacc, 0, 0, 0);
    }
    if (half < 2) {
#pragma unroll
      for (int r = 0; r < 4; ++r)
        Wred[wave][(h * 8 + half * 4 + r) * 16 + rlo] = wacc[r];
    }
  }
  __syncthreads();
  int tid = threadIdx.x;
#pragma unroll
  for (int r2 = 0; r2 < 2; ++r2) {
    int idx = tid + r2 * 256;
    atomicAdd(&Wg[b * 512 + idx],
              Wred[0][idx] + Wred[1][idx] + Wred[2][idx] + Wred[3][idx]);
  }
}

// ---------------------------------------------------------------------------
// K3: one wave per (batch,slot). grid 512 x 64.
// ---------------------------------------------------------------------------
template <int IT>
__global__ __launch_bounds__(64) void k_update(
    float* __restrict__ Sg, float* __restrict__ Wg,
    float* __restrict__ slots_buf,
    const float* __restrict__ W_ih, const float* __restrict__ W_hh,
    const float* __restrict__ b_ih, const float* __restrict__ b_hh,
    const float* __restrict__ g_mlp, const float* __restrict__ b_mlp,
    const float* __restrict__ W1, const float* __restrict__ b1,
    const float* __restrict__ W2, const float* __restrict__ b2,
    const float* __restrict__ g_slot, const float* __restrict__ b_slot,
    const float* __restrict__ Wq, float* __restrict__ qbuf,
    float* __restrict__ out_slots) {
  constexpr int compute_next = (IT < 2);
  constexpr int write_out = (IT == 2);
  int b = blockIdx.x >> 3, s = blockIdx.x & 7, d = threadIdx.x;
  __shared__ float upd_s[64], h_s[64], lnm_s[64], h1_s[128], l2_s[64];
  float hp = slots_buf[(b * 8 + s) * 64 + d];
  int hh = d >> 4, dh = d & 15, hq = hh * 8 + s;
  float denom = Sg[b * 32 + hq] + 8192.f * 1e-8f;
  float updv = Wg[(b * 32 + hq) * 16 + dh] / denom;
  upd_s[d] = updv; h_s[d] = hp;
  __syncthreads();
  float xr = b_ih[d], xz = b_ih[64 + d], xn = b_ih[128 + d];
  float hr = b_hh[d], hz = b_hh[64 + d], hv3 = b_hh[128 + d];
  const float* wi0 = W_ih + d * 64;
  const float* wi1 = W_ih + (64 + d) * 64;
  const float* wi2 = W_ih + (128 + d) * 64;
  const float* wh0 = W_hh + d * 64;
  const float* wh1 = W_hh + (64 + d) * 64;
  const float* wh2 = W_hh + (128 + d) * 64;
#pragma unroll 4
  for (int jj = 0; jj < 16; ++jj) {
    f32x4 u = *(const f32x4*)&upd_s[jj * 4];
    f32x4 hvv = *(const f32x4*)&h_s[jj * 4];
    f32x4 a0 = *(const f32x4*)&wi0[jj * 4];
    f32x4 a1 = *(const f32x4*)&wi1[jj * 4];
    f32x4 a2 = *(const f32x4*)&wi2[jj * 4];
    f32x4 c0 = *(const f32x4*)&wh0[jj * 4];
    f32x4 c1 = *(const f32x4*)&wh1[jj * 4];
    f32x4 c2 = *(const f32x4*)&wh2[jj * 4];
#pragma unroll
    for (int i = 0; i < 4; ++i) {
      xr = fmaf(u[i], a0[i], xr);  xz = fmaf(u[i], a1[i], xz);  xn = fmaf(u[i], a2[i], xn);
      hr = fmaf(hvv[i], c0[i], hr); hz = fmaf(hvv[i], c1[i], hz); hv3 = fmaf(hvv[i], c2[i], hv3);
    }
  }
  float r = sigm(xr + hr);
  float z = sigm(xz + hz);
  float n = tanhf(xn + r * hv3);
  float hn = (1.f - z) * n + z * hp;
  float sum = hn, sq = hn * hn;
#pragma unroll
  for (int msk = 1; msk < 64; msk <<= 1) { sum += __shfl_xor(sum, msk); sq += __shfl_xor(sq, msk); }
  float mean = sum * 0.015625f, var = sq * 0.015625f - mean * mean;
  float lnv = (hn - mean) * rsqrtf(var + 1e-5f) * g_mlp[d] + b_mlp[d];
  lnm_s[d] = lnv;
  __syncthreads();
  float a1a = b1[d], a1b = b1[64 + d];
#pragma unroll 8
  for (int j = 0; j < 64; ++j) {
    float lj = lnm_s[j];
    a1a = fmaf(lj, W1[j * 128 + d], a1a);
    a1b = fmaf(lj, W1[j * 128 + 64 + d], a1b);
  }
  h1_s[d] = fmaxf(a1a, 0.f); h1_s[64 + d] = fmaxf(a1b, 0.f);
  __syncthreads();
  float a2 = b2[d];
#pragma unroll 8
  for (int c = 0; c < 128; ++c) a2 = fmaf(h1_s[c], W2[c * 64 + d], a2);
  float outv = hn + a2;
  slots_buf[(b * 8 + s) * 64 + d] = outv;
  if (write_out) out_slots[(b * 8 + s) * 64 + d] = outv;
  if (compute_next) {
    float sum2 = outv, sq2 = outv * outv;
#pragma unroll
    for (int msk = 1; msk < 64; msk <<= 1) { sum2 += __shfl_xor(sum2, msk); sq2 += __shfl_xor(sq2, msk); }
    float mean2 = sum2 * 0.015625f, var2 = sq2 * 0.015625f - mean2 * mean2;
    float l2 = (outv - mean2) * rsqrtf(var2 + 1e-5f) * g_slot[d] + b_slot[d];
    l2_s[d] = l2;
    __syncthreads();
    float acc = 0.f;
#pragma unroll 8
    for (int j = 0; j < 64; ++j) acc = fmaf(l2_s[j], Wq[j * 64 + d], acc);
    acc *= 0.25f;
    qbuf[(b * 32 + hq) * 16 + dh] = acc;
    if (d < 4) Sg[b * 32 + d * 8 + s] = 0.f;
    Wg[(b * 32 + hq) * 16 + dh] = 0.f;
  }
}

extern "C" void kernel_launch(void* const* d_in, const int* in_sizes, int n_in,
                              void* d_out, int out_size, void* d_ws, size_t ws_size,
                              hipStream_t stream) {
  const float* inputs    = (const float*)d_in[0];
  const float* slots     = (const float*)d_in[1];
  const float* ln_in_g   = (const float*)d_in[2];
  const float* ln_in_b   = (const float*)d_in[3];
  const float* ln_slot_g = (const float*)d_in[4];
  const float* ln_slot_b = (const float*)d_in[5];
  const float* ln_mlp_g  = (const float*)d_in[6];
  const float* ln_mlp_b  = (const float*)d_in[7];
  const float* Wq        = (const float*)d_in[8];
  const float* Wk        = (const float*)d_in[9];
  const float* Wv        = (const float*)d_in[10];
  const float* W_ih      = (const float*)d_in[11];
  const float* W_hh      = (const float*)d_in[12];
  const float* b_ih      = (const float*)d_in[13];
  const float* b_hh      = (const float*)d_in[14];
  const float* mlp_W1    = (const float*)d_in[15];
  const float* mlp_b1    = (const float*)d_in[16];
  const float* mlp_W2    = (const float*)d_in[17];
  const float* mlp_b2    = (const float*)d_in[18];

  float* out_slots = (float*)d_out;                 // [64*8*64]
  float* out_vis   = out_slots + 64 * 8 * 64;       // [64*8192*8]

  char* ws = (char*)d_ws;
  unsigned short* kv = (unsigned short*)ws;         // 64*8192*128 bf16 = 128 MiB
  size_t off = (size_t)64 * 8192 * 128 * 2;
  float* qbuf      = (float*)(ws + off); off += (size_t)64 * 32 * 16 * 4;
  float* Sg        = (float*)(ws + off); off += (size_t)64 * 32 * 4;
  float* Wg        = (float*)(ws + off); off += (size_t)64 * 512 * 4;
  float* slots_buf = (float*)(ws + off); off += (size_t)64 * 512 * 4;
  unsigned short* wf = (unsigned short*)(ws + off); off += (size_t)1024 * 8 * 2;
  unsigned short* qfrag = (unsigned short*)(ws + off); off += (size_t)64 * 4 * 64 * 8 * 2;

  hipLaunchKernelGGL(k_wprep, dim3(4), dim3(256), 0, stream, Wk, Wv, wf);
  hipLaunchKernelGGL(k_proj, dim3(1024), dim3(256), 0, stream,
                     inputs, ln_in_g, ln_in_b, wf, kv);
  hipLaunchKernelGGL(k_prep, dim3(512), dim3(64), 0, stream,
                     slots, ln_slot_g, ln_slot_b, Wq, slots_buf, qbuf, Sg, Wg);
  hipLaunchKernelGGL(k_qfrag, dim3(64), dim3(64), 0, stream, qbuf, qfrag);

  hipLaunchKernelGGL((k_attn<0>), dim3(64 * 32), dim3(256), 0, stream,
                     kv, qfrag, Sg, Wg, out_vis);
  hipLaunchKernelGGL((k_update<0>), dim3(512), dim3(64), 0, stream,
                     Sg, Wg, slots_buf, W_ih, W_hh, b_ih, b_hh,
                     ln_mlp_g, ln_mlp_b, mlp_W1, mlp_b1, mlp_W2, mlp_b2,
                     ln_slot_g, ln_slot_b, Wq, qbuf, out_slots);
  hipLaunchKernelGGL(k_qfrag, dim3(64), dim3(64), 0, stream, qbuf, qfrag);
  hipLaunchKernelGGL((k_attn<1>), dim3(64 * 32), dim3(256), 0, stream,
                     kv, qfrag, Sg, Wg, out_vis);
  hipLaunchKernelGGL((k_update<1>), dim3(512), dim3(64), 0, stream,
                     Sg, Wg, slots_buf, W_ih, W_hh, b_ih, b_hh,
                     ln_mlp_g, ln_mlp_b, mlp_W1, mlp_b1, mlp_W2, mlp_b2,
                     ln_slot_g, ln_slot_b, Wq, qbuf, out_slots);
  hipLaunchKernelGGL(k_qfrag, dim3(64), dim3(64), 0, stream, qbuf, qfrag);
  hipLaunchKernelGGL((k_attn<2>), dim3(64 * 32), dim3(256), 0, stream,
                     kv, qfrag, Sg, Wg, out_vis);
  hipLaunchKernelGGL((k_update<2>), dim3(512), dim3(64), 0, stream,
                     Sg, Wg, slots_buf, W_ih, W_hh, b_ih, b_hh,
                     ln_mlp_g, ln_mlp_b, mlp_W1, mlp_b1, mlp_W2, mlp_b2,
                     ln_slot_g, ln_slot_b, Wq, qbuf, out_slots);
}

// Round 9
// 467.107 us; speedup vs baseline: 1.0013x; 1.0013x over previous
//
#include <hip/hip_runtime.h>

#define NKV 8192
#define NB 64

typedef __attribute__((ext_vector_type(8))) short short8;
typedef __attribute__((ext_vector_type(8))) unsigned short ushort8;
typedef __attribute__((ext_vector_type(4))) unsigned short usx4;
typedef __attribute__((ext_vector_type(4))) float f32x4;

__device__ __forceinline__ float bf2f(unsigned short u) {
  return __uint_as_float(((unsigned int)u) << 16);
}
__device__ __forceinline__ unsigned short f2bf(float f) {
  unsigned int x = __float_as_uint(f);
  return (unsigned short)((x + 0x7fffu + ((x >> 16) & 1u)) >> 16);
}
__device__ __forceinline__ float sigm(float x) { return 1.f / (1.f + __expf(-x)); }

// ---------------------------------------------------------------------------
// K0: convert Wk/Wv to bf16 MFMA fragments once (W^T chunks).
// ---------------------------------------------------------------------------
__global__ __launch_bounds__(256) void k_wprep(
    const float* __restrict__ Wk, const float* __restrict__ Wv,
    unsigned short* __restrict__ wf) {
  int idx = blockIdx.x * 256 + threadIdx.x;  // 0..1023
  int lane = idx & 63, ct = (idx >> 6) & 7, kf = idx >> 9;
  int half = lane >> 4, rlo = lane & 15;
  const float* W = (ct < 4) ? Wk : Wv;
  int cc = (ct & 3) * 16 + rlo;
  ushort8 pk;
#pragma unroll
  for (int i = 0; i < 8; ++i)
    pk[i] = f2bf(W[(kf * 32 + half * 8 + i) * 64 + cc]);
  *(ushort8*)(wf + (size_t)idx * 8) = pk;
}

// ---------------------------------------------------------------------------
// K0b: transpose GRU weights once: WT[j][o] = W[o][j]  (192x64 -> 64x192).
// ---------------------------------------------------------------------------
__global__ __launch_bounds__(256) void k_gruprep(
    const float* __restrict__ W_ih, const float* __restrict__ W_hh,
    float* __restrict__ WihT, float* __restrict__ WhhT) {
  int idx = blockIdx.x * 256 + threadIdx.x;
  if (idx < 192 * 64) {
    int o = idx >> 6, j = idx & 63;
    WihT[j * 192 + o] = W_ih[idx];
    WhhT[j * 192 + o] = W_hh[idx];
  }
}

// ---------------------------------------------------------------------------
// K1: LN + k/v projection. grid 4096 x 256; 2 tiles of 16 tokens per wave.
// ---------------------------------------------------------------------------
__global__ __launch_bounds__(256) void k_proj(
    const float* __restrict__ x, const float* __restrict__ gin,
    const float* __restrict__ bin, const unsigned short* __restrict__ wf,
    unsigned short* __restrict__ kv) {
  const int lane = threadIdx.x & 63;
  const int wave = threadIdx.x >> 6;
  const int half = lane >> 4, rlo = lane & 15;

  short8 bfr[2][8];
  const ushort8* wf8 = (const ushort8*)wf;
#pragma unroll
  for (int kf = 0; kf < 2; ++kf)
#pragma unroll
    for (int ct = 0; ct < 8; ++ct)
      bfr[kf][ct] = (short8)wf8[(kf * 8 + ct) * 64 + lane];

  float g0[8], g1[8], bb0[8], bb1[8];
#pragma unroll
  for (int i = 0; i < 8; ++i) {
    g0[i] = gin[half * 8 + i];      bb0[i] = bin[half * 8 + i];
    g1[i] = gin[32 + half * 8 + i]; bb1[i] = bin[32 + half * 8 + i];
  }
  long tok0 = ((long)blockIdx.x * 4 + wave) * 32;
#pragma unroll
  for (int tile = 0; tile < 2; ++tile) {
    long row = tok0 + tile * 16 + rlo;
    const f32x4* p4 = (const f32x4*)(x + row * 64);
    f32x4 u0 = p4[half * 2], u1 = p4[half * 2 + 1];
    f32x4 u2 = p4[8 + half * 2], u3 = p4[9 + half * 2];
    float s = 0.f, ss = 0.f;
#pragma unroll
    for (int i = 0; i < 4; ++i) {
      s += u0[i] + u1[i] + u2[i] + u3[i];
      ss = fmaf(u0[i], u0[i], fmaf(u1[i], u1[i], fmaf(u2[i], u2[i], fmaf(u3[i], u3[i], ss))));
    }
    s += __shfl_xor(s, 16); ss += __shfl_xor(ss, 16);
    s += __shfl_xor(s, 32); ss += __shfl_xor(ss, 32);
    float m = s * 0.015625f;
    float var = ss * 0.015625f - m * m;
    float rs = rsqrtf(var + 1e-5f);
    short8 a0, a1;
#pragma unroll
    for (int i = 0; i < 4; ++i) {
      a0[i]     = (short)f2bf((u0[i] - m) * rs * g0[i]     + bb0[i]);
      a0[i + 4] = (short)f2bf((u1[i] - m) * rs * g0[i + 4] + bb0[i + 4]);
      a1[i]     = (short)f2bf((u2[i] - m) * rs * g1[i]     + bb1[i]);
      a1[i + 4] = (short)f2bf((u3[i] - m) * rs * g1[i + 4] + bb1[i + 4]);
    }
    long t = tok0 + tile * 16 + rlo;
#pragma unroll
    for (int ct = 0; ct < 8; ++ct) {
      f32x4 acc = {0.f, 0.f, 0.f, 0.f};
      acc = __builtin_amdgcn_mfma_f32_16x16x32_bf16(bfr[0][ct], a0, acc, 0, 0, 0);
      acc = __builtin_amdgcn_mfma_f32_16x16x32_bf16(bfr[1][ct], a1, acc, 0, 0, 0);
      float sc = (ct < 4) ? 0.25f : 1.f;
      usx4 pk;
#pragma unroll
      for (int r = 0; r < 4; ++r) pk[r] = f2bf(acc[r] * sc);
      *(usx4*)(kv + t * 128 + ct * 16 + half * 4) = pk;
    }
  }
}

// ---------------------------------------------------------------------------
// K_prep: one wave per (batch,slot). grid 512 x 64.
// ---------------------------------------------------------------------------
__global__ __launch_bounds__(64) void k_prep(
    const float* __restrict__ slots_in, const float* __restrict__ g_slot,
    const float* __restrict__ b_slot, const float* __restrict__ Wq,
    float* __restrict__ slots_buf, float* __restrict__ qbuf,
    float* __restrict__ Sg, float* __restrict__ Wg) {
  int b = blockIdx.x >> 3, s = blockIdx.x & 7, d = threadIdx.x;
  __shared__ float l2_s[64];
  float x = slots_in[(b * 8 + s) * 64 + d];
  slots_buf[(b * 8 + s) * 64 + d] = x;
  float sum = x, sq = x * x;
#pragma unroll
  for (int msk = 1; msk < 64; msk <<= 1) { sum += __shfl_xor(sum, msk); sq += __shfl_xor(sq, msk); }
  float mean = sum * 0.015625f, var = sq * 0.015625f - mean * mean;
  float ln = (x - mean) * rsqrtf(var + 1e-5f) * g_slot[d] + b_slot[d];
  l2_s[d] = ln;
  __syncthreads();
  float acc = 0.f;
#pragma unroll 8
  for (int j = 0; j < 64; ++j) acc = fmaf(l2_s[j], Wq[j * 64 + d], acc);
  acc *= 0.25f;
  int hh = d >> 4, dh = d & 15, hq = hh * 8 + s;
  qbuf[(b * 32 + hq) * 16 + dh] = acc;
  if (d < 4) Sg[b * 32 + d * 8 + s] = 0.f;
  Wg[(b * 32 + hq) * 16 + dh] = 0.f;
}

// ---------------------------------------------------------------------------
// K_qfrag: build block-diagonal Qmat^T bf16 A-fragments per batch.
// ---------------------------------------------------------------------------
__global__ __launch_bounds__(64) void k_qfrag(
    const float* __restrict__ qbuf, unsigned short* __restrict__ qfrag) {
  int b = blockIdx.x, lane = threadIdx.x;
  int half = lane >> 4, rlo = lane & 15;
#pragma unroll
  for (int m = 0; m < 2; ++m) {
    int hq = m * 16 + rlo, h = hq >> 3;
#pragma unroll
    for (int kc = 0; kc < 2; ++kc) {
      ushort8 pk;
#pragma unroll
      for (int i = 0; i < 8; ++i) {
        int d = kc * 32 + half * 8 + i;
        float v = ((d >> 4) == h) ? qbuf[(b * 32 + hq) * 16 + (d & 15)] : 0.f;
        pk[i] = f2bf(v);
      }
      *(ushort8*)(qfrag + ((size_t)(b * 4 + m * 2 + kc) * 64 + lane) * 8) = pk;
    }
  }
}

// ---------------------------------------------------------------------------
// K2 v2: per wave 64 tokens.
//  - stage V rows coalesced into LDS Vs[64][66] (pad 66: conflict-free frags)
//  - QK: 4 MFMA per 16-token tile (coalesced short8 K loads)
//  - softmax over 32 hq: local 8-sum + shfl_xor(16,32)
//  - PV: A-frags from P (stride 34), B-frags from Vs, 16 MFMAs
//  - Wred aliased onto P region after barrier; cross-wave sum; atomics
// grid (B*32) x 256.
// ---------------------------------------------------------------------------
template <int IT>
__global__ __launch_bounds__(256) void k_attn(
    const unsigned short* __restrict__ kv, const unsigned short* __restrict__ qfrag,
    float* __restrict__ Sg, float* __restrict__ Wg,
    float* __restrict__ vis) {
  constexpr bool last = (IT == 2);
  int b = blockIdx.x >> 5, chunk = blockIdx.x & 31;
  int lane = threadIdx.x & 63, wave = threadIdx.x >> 6;
  int half = lane >> 4, rlo = lane & 15;
  __shared__ unsigned short P[4][64 * 34];   // also reused as Wred (f32[512])
  __shared__ unsigned short Vs[4][64 * 66];
  int t0 = chunk * 256 + wave * 64;
  long gbase = ((long)(b * NKV) + t0) * 128;

  // ---- stage V (coalesced): 8 lanes per token row, 8 rows per instr ----
  {
    int vtok = lane >> 3, vcol = (lane & 7) * 8;
#pragma unroll
    for (int r = 0; r < 8; ++r) {
      int tr = r * 8 + vtok;
      ushort8 vv = *(const ushort8*)(kv + gbase + (long)tr * 128 + 64 + vcol);
      *(ushort8*)(&Vs[wave][tr * 66 + vcol]) = vv;
    }
  }

  short8 afr[2][2];
  const ushort8* qf8 = (const ushort8*)qfrag;
#pragma unroll
  for (int m = 0; m < 2; ++m)
#pragma unroll
    for (int kc = 0; kc < 2; ++kc)
      afr[m][kc] = (short8)qf8[(b * 4 + m * 2 + kc) * 64 + lane];

  float Sacc[2][4];
#pragma unroll
  for (int m = 0; m < 2; ++m)
#pragma unroll
    for (int r = 0; r < 4; ++r) Sacc[m][r] = 0.f;

  // ---- QK + softmax per 16-token tile ----
#pragma unroll
  for (int nt = 0; nt < 4; ++nt) {
    long rowb = gbase + (long)(nt * 16 + rlo) * 128;
    short8 bk0 = *(const short8*)(kv + rowb + half * 8);
    short8 bk1 = *(const short8*)(kv + rowb + 32 + half * 8);
    f32x4 acc0 = {0.f, 0.f, 0.f, 0.f}, acc1 = {0.f, 0.f, 0.f, 0.f};
    acc0 = __builtin_amdgcn_mfma_f32_16x16x32_bf16(afr[0][0], bk0, acc0, 0, 0, 0);
    acc0 = __builtin_amdgcn_mfma_f32_16x16x32_bf16(afr[0][1], bk1, acc0, 0, 0, 0);
    acc1 = __builtin_amdgcn_mfma_f32_16x16x32_bf16(afr[1][0], bk0, acc1, 0, 0, 0);
    acc1 = __builtin_amdgcn_mfma_f32_16x16x32_bf16(afr[1][1], bk1, acc1, 0, 0, 0);
    float e0[4], e1[4], ssum = 0.f;
#pragma unroll
    for (int r = 0; r < 4; ++r) {
      e0[r] = __expf(acc0[r]); e1[r] = __expf(acc1[r]);
      ssum += e0[r] + e1[r];
    }
    ssum += __shfl_xor(ssum, 16);
    ssum += __shfl_xor(ssum, 32);
    float rs = __builtin_amdgcn_rcpf(ssum);
    float a0[4], a1[4];
#pragma unroll
    for (int r = 0; r < 4; ++r) {
      a0[r] = e0[r] * rs; a1[r] = e1[r] * rs;
      Sacc[0][r] += a0[r]; Sacc[1][r] += a1[r];
    }
    int off = (nt * 16 + rlo) * 34;
    unsigned int w00 = (unsigned int)f2bf(a0[0]) | ((unsigned int)f2bf(a0[1]) << 16);
    unsigned int w01 = (unsigned int)f2bf(a0[2]) | ((unsigned int)f2bf(a0[3]) << 16);
    unsigned int w10 = (unsigned int)f2bf(a1[0]) | ((unsigned int)f2bf(a1[1]) << 16);
    unsigned int w11 = (unsigned int)f2bf(a1[2]) | ((unsigned int)f2bf(a1[3]) << 16);
    *(unsigned int*)(&P[wave][off + half * 4])          = w00;
    *(unsigned int*)(&P[wave][off + half * 4 + 2])      = w01;
    *(unsigned int*)(&P[wave][off + 16 + half * 4])     = w10;
    *(unsigned int*)(&P[wave][off + 16 + half * 4 + 2]) = w11;
    if (last) {
      float vl[4];
#pragma unroll
      for (int r = 0; r < 4; ++r) {
        vl[r] = a0[r] + a1[r];
        vl[r] += __shfl_xor(vl[r], 32);
      }
      if (half < 2) {
        long tt = (long)b * NKV + t0 + nt * 16 + rlo;
#pragma unroll
        for (int r = 0; r < 4; ++r) vis[tt * 8 + (half & 1) * 4 + r] = vl[r];
      }
    }
  }
  // ---- S reduce over rlo + atomics ----
#pragma unroll
  for (int m = 0; m < 2; ++m)
#pragma unroll
    for (int r = 0; r < 4; ++r) {
      Sacc[m][r] += __shfl_xor(Sacc[m][r], 1);
      Sacc[m][r] += __shfl_xor(Sacc[m][r], 2);
      Sacc[m][r] += __shfl_xor(Sacc[m][r], 4);
      Sacc[m][r] += __shfl_xor(Sacc[m][r], 8);
    }
  if (rlo == 0) {
#pragma unroll
    for (int m = 0; m < 2; ++m)
#pragma unroll
      for (int r = 0; r < 4; ++r)
        atomicAdd(&Sg[b * 32 + m * 16 + half * 4 + r], Sacc[m][r]);
  }
  // ---- PV: A from P, B from Vs ----
  short8 pa[2][2];
#pragma unroll
  for (int m = 0; m < 2; ++m)
#pragma unroll
    for (int kc = 0; kc < 2; ++kc) {
      short8 f;
#pragma unroll
      for (int i = 0; i < 8; ++i)
        f[i] = (short)P[wave][(kc * 32 + half * 8 + i) * 34 + m * 16 + rlo];
      pa[m][kc] = f;
    }
  float* Wred = (float*)&P[wave][0];
  int myh = half >> 1;
#pragma unroll
  for (int h = 0; h < 4; ++h) {
    short8 vb0, vb1;
#pragma unroll
    for (int i = 0; i < 8; ++i) {
      vb0[i] = (short)Vs[wave][(half * 8 + i) * 66 + h * 16 + rlo];
      vb1[i] = (short)Vs[wave][(32 + half * 8 + i) * 66 + h * 16 + rlo];
    }
#pragma unroll
    for (int m = 0; m < 2; ++m) {
      f32x4 wacc = {0.f, 0.f, 0.f, 0.f};
      wacc = __builtin_amdgcn_mfma_f32_16x16x32_bf16(pa[m][0], vb0, wacc, 0, 0, 0);
      wacc = __builtin_amdgcn_mfma_f32_16x16x32_bf16(pa[m][1], vb1, wacc, 0, 0, 0);
      if (h == m * 2 + myh) {
#pragma unroll
        for (int r = 0; r < 4; ++r)
          Wred[(m * 16 + half * 4 + r) * 16 + rlo] = wacc[r];
      }
    }
  }
  __syncthreads();
  int tid = threadIdx.x;
#pragma unroll
  for (int r2 = 0; r2 < 2; ++r2) {
    int idx = tid + r2 * 256;
    float v = ((const float*)&P[0][0])[idx] + ((const float*)&P[1][0])[idx] +
              ((const float*)&P[2][0])[idx] + ((const float*)&P[3][0])[idx];
    atomicAdd(&Wg[b * 512 + idx], v);
  }
}

// ---------------------------------------------------------------------------
// K3 v2: coalesced GRU gate loads via transposed weights. grid 512 x 64.
// ---------------------------------------------------------------------------
template <int IT>
__global__ __launch_bounds__(64) void k_update(
    float* __restrict__ Sg, float* __restrict__ Wg,
    float* __restrict__ slots_buf,
    const float* __restrict__ WihT, const float* __restrict__ WhhT,
    const float* __restrict__ b_ih, const float* __restrict__ b_hh,
    const float* __restrict__ g_mlp, const float* __restrict__ b_mlp,
    const float* __restrict__ W1, const float* __restrict__ b1,
    const float* __restrict__ W2, const float* __restrict__ b2,
    const float* __restrict__ g_slot, const float* __restrict__ b_slot,
    const float* __restrict__ Wq, float* __restrict__ qbuf,
    float* __restrict__ out_slots) {
  constexpr int compute_next = (IT < 2);
  constexpr int write_out = (IT == 2);
  int b = blockIdx.x >> 3, s = blockIdx.x & 7, d = threadIdx.x;
  __shared__ float upd_s[64], h_s[64], lnm_s[64], h1_s[128], l2_s[64];
  float hp = slots_buf[(b * 8 + s) * 64 + d];
  int hh = d >> 4, dh = d & 15, hq = hh * 8 + s;
  float denom = Sg[b * 32 + hq] + 8192.f * 1e-8f;
  float updv = Wg[(b * 32 + hq) * 16 + dh] / denom;
  upd_s[d] = updv; h_s[d] = hp;
  __syncthreads();
  float xr = b_ih[d], xz = b_ih[64 + d], xn = b_ih[128 + d];
  float hr = b_hh[d], hz = b_hh[64 + d], hn3 = b_hh[128 + d];
#pragma unroll 8
  for (int j = 0; j < 64; ++j) {
    float uj = upd_s[j], hj = h_s[j];
    xr = fmaf(uj, WihT[j * 192 + d], xr);
    xz = fmaf(uj, WihT[j * 192 + 64 + d], xz);
    xn = fmaf(uj, WihT[j * 192 + 128 + d], xn);
    hr = fmaf(hj, WhhT[j * 192 + d], hr);
    hz = fmaf(hj, WhhT[j * 192 + 64 + d], hz);
    hn3 = fmaf(hj, WhhT[j * 192 + 128 + d], hn3);
  }
  float r = sigm(xr + hr);
  float z = sigm(xz + hz);
  float n = tanhf(xn + r * hn3);
  float hn = (1.f - z) * n + z * hp;
  float sum = hn, sq = hn * hn;
#pragma unroll
  for (int msk = 1; msk < 64; msk <<= 1) { sum += __shfl_xor(sum, msk); sq += __shfl_xor(sq, msk); }
  float mean = sum * 0.015625f, var = sq * 0.015625f - mean * mean;
  float lnv = (hn - mean) * rsqrtf(var + 1e-5f) * g_mlp[d] + b_mlp[d];
  lnm_s[d] = lnv;
  __syncthreads();
  float a1a = b1[d], a1b = b1[64 + d];
#pragma unroll 8
  for (int j = 0; j < 64; ++j) {
    float lj = lnm_s[j];
    a1a = fmaf(lj, W1[j * 128 + d], a1a);
    a1b = fmaf(lj, W1[j * 128 + 64 + d], a1b);
  }
  h1_s[d] = fmaxf(a1a, 0.f); h1_s[64 + d] = fmaxf(a1b, 0.f);
  __syncthreads();
  float a2 = b2[d];
#pragma unroll 8
  for (int c = 0; c < 128; ++c) a2 = fmaf(h1_s[c], W2[c * 64 + d], a2);
  float outv = hn + a2;
  slots_buf[(b * 8 + s) * 64 + d] = outv;
  if (write_out) out_slots[(b * 8 + s) * 64 + d] = outv;
  if (compute_next) {
    float sum2 = outv, sq2 = outv * outv;
#pragma unroll
    for (int msk = 1; msk < 64; msk <<= 1) { sum2 += __shfl_xor(sum2, msk); sq2 += __shfl_xor(sq2, msk); }
    float mean2 = sum2 * 0.015625f, var2 = sq2 * 0.015625f - mean2 * mean2;
    float l2 = (outv - mean2) * rsqrtf(var2 + 1e-5f) * g_slot[d] + b_slot[d];
    l2_s[d] = l2;
    __syncthreads();
    float acc = 0.f;
#pragma unroll 8
    for (int j = 0; j < 64; ++j) acc = fmaf(l2_s[j], Wq[j * 64 + d], acc);
    acc *= 0.25f;
    qbuf[(b * 32 + hq) * 16 + dh] = acc;
    if (d < 4) Sg[b * 32 + d * 8 + s] = 0.f;
    Wg[(b * 32 + hq) * 16 + dh] = 0.f;
  }
}

extern "C" void kernel_launch(void* const* d_in, const int* in_sizes, int n_in,
                              void* d_out, int out_size, void* d_ws, size_t ws_size,
                              hipStream_t stream) {
  const float* inputs    = (const float*)d_in[0];
  const float* slots     = (const float*)d_in[1];
  const float* ln_in_g   = (const float*)d_in[2];
  const float* ln_in_b   = (const float*)d_in[3];
  const float* ln_slot_g = (const float*)d_in[4];
  const float* ln_slot_b = (const float*)d_in[5];
  const float* ln_mlp_g  = (const float*)d_in[6];
  const float* ln_mlp_b  = (const float*)d_in[7];
  const float* Wq        = (const float*)d_in[8];
  const float* Wk        = (const float*)d_in[9];
  const float* Wv        = (const float*)d_in[10];
  const float* W_ih      = (const float*)d_in[11];
  const float* W_hh      = (const float*)d_in[12];
  const float* b_ih      = (const float*)d_in[13];
  const float* b_hh      = (const float*)d_in[14];
  const float* mlp_W1    = (const float*)d_in[15];
  const float* mlp_b1    = (const float*)d_in[16];
  const float* mlp_W2    = (const float*)d_in[17];
  const float* mlp_b2    = (const float*)d_in[18];

  float* out_slots = (float*)d_out;                 // [64*8*64]
  float* out_vis   = out_slots + 64 * 8 * 64;       // [64*8192*8]

  char* ws = (char*)d_ws;
  unsigned short* kv = (unsigned short*)ws;         // 128 MiB
  size_t off = (size_t)64 * 8192 * 128 * 2;
  float* qbuf      = (float*)(ws + off); off += (size_t)64 * 32 * 16 * 4;
  float* Sg        = (float*)(ws + off); off += (size_t)64 * 32 * 4;
  float* Wg        = (float*)(ws + off); off += (size_t)64 * 512 * 4;
  float* slots_buf = (float*)(ws + off); off += (size_t)64 * 512 * 4;
  unsigned short* wf = (unsigned short*)(ws + off); off += (size_t)1024 * 8 * 2;
  unsigned short* qfrag = (unsigned short*)(ws + off); off += (size_t)64 * 4 * 64 * 8 * 2;
  float* WihT = (float*)(ws + off); off += (size_t)192 * 64 * 4;
  float* WhhT = (float*)(ws + off); off += (size_t)192 * 64 * 4;

  hipLaunchKernelGGL(k_wprep, dim3(4), dim3(256), 0, stream, Wk, Wv, wf);
  hipLaunchKernelGGL(k_gruprep, dim3(48), dim3(256), 0, stream, W_ih, W_hh, WihT, WhhT);
  hipLaunchKernelGGL(k_proj, dim3(4096), dim3(256), 0, stream,
                     inputs, ln_in_g, ln_in_b, wf, kv);
  hipLaunchKernelGGL(k_prep, dim3(512), dim3(64), 0, stream,
                     slots, ln_slot_g, ln_slot_b, Wq, slots_buf, qbuf, Sg, Wg);
  hipLaunchKernelGGL(k_qfrag, dim3(64), dim3(64), 0, stream, qbuf, qfrag);

  hipLaunchKernelGGL((k_attn<0>), dim3(64 * 32), dim3(256), 0, stream,
                     kv, qfrag, Sg, Wg, out_vis);
  hipLaunchKernelGGL((k_update<0>), dim3(512), dim3(64), 0, stream,
                     Sg, Wg, slots_buf, WihT, WhhT, b_ih, b_hh,
                     ln_mlp_g, ln_mlp_b, mlp_W1, mlp_b1, mlp_W2, mlp_b2,
                     ln_slot_g, ln_slot_b, Wq, qbuf, out_slots);
  hipLaunchKernelGGL(k_qfrag, dim3(64), dim3(64), 0, stream, qbuf, qfrag);
  hipLaunchKernelGGL((k_attn<1>), dim3(64 * 32), dim3(256), 0, stream,
                     kv, qfrag, Sg, Wg, out_vis);
  hipLaunchKernelGGL((k_update<1>), dim3(512), dim3(64), 0, stream,
                     Sg, Wg, slots_buf, WihT, WhhT, b_ih, b_hh,
                     ln_mlp_g, ln_mlp_b, mlp_W1, mlp_b1, mlp_W2, mlp_b2,
                     ln_slot_g, ln_slot_b, Wq, qbuf, out_slots);
  hipLaunchKernelGGL(k_qfrag, dim3(64), dim3(64), 0, stream, qbuf, qfrag);
  hipLaunchKernelGGL((k_attn<2>), dim3(64 * 32), dim3(256), 0, stream,
                     kv, qfrag, Sg, Wg, out_vis);
  hipLaunchKernelGGL((k_update<2>), dim3(512), dim3(64), 0, stream,
                     Sg, Wg, slots_buf, WihT, WhhT, b_ih, b_hh,
                     ln_mlp_g, ln_mlp_b, mlp_W1, mlp_b1, mlp_W2, mlp_b2,
                     ln_slot_g, ln_slot_b, Wq, qbuf, out_slots);
}